// Round 1
// baseline (224.902 us; speedup 1.0000x reference)
//
#include <hip/hip_runtime.h>

constexpr int B = 64;
constexpr int N = 8192;
constexpr int D = 256;
constexpr int K = 128;

// --- Kernel 1: per-row L2 norm (sum of squares over D) ---------------------
// One wave (64 lanes) per row; each lane loads one float4 (4 floats),
// so a wave covers exactly D=256 floats with a single coalesced 1KiB access.
__global__ __launch_bounds__(256) void norms_kernel(const float* __restrict__ x,
                                                    float* __restrict__ norms) {
    const int row  = blockIdx.x * 4 + (threadIdx.x >> 6);   // 4 waves per block
    const int lane = threadIdx.x & 63;
    const float4 v = reinterpret_cast<const float4*>(x + (size_t)row * D)[lane];
    float s = v.x * v.x + v.y * v.y + v.z * v.z + v.w * v.w;
    #pragma unroll
    for (int off = 32; off > 0; off >>= 1)
        s += __shfl_xor(s, off, 64);
    if (lane == 0) norms[row] = s;
}

// --- Kernel 2: per-batch top-K by descending norm, stable (lower idx first) -
// One block (1024 threads) per batch. Keys packed so that a plain descending
// u64 sort gives: primary = norm (float bits, nonnegative => monotone as uint),
// secondary = smaller index first (store N-1-i in low 32 bits).
__global__ __launch_bounds__(1024) void topk_kernel(const float* __restrict__ norms,
                                                    int* __restrict__ idx_out) {
    __shared__ unsigned long long keys[N];   // 64 KiB LDS
    const int b = blockIdx.x;
    const float* nb = norms + (size_t)b * N;

    for (int i = threadIdx.x; i < N; i += 1024) {
        unsigned int bits = __float_as_uint(nb[i]);          // norms >= 0
        keys[i] = ((unsigned long long)bits << 32) | (unsigned int)(N - 1 - i);
    }
    __syncthreads();

    // Bitonic sort, descending.
    for (int k = 2; k <= N; k <<= 1) {
        for (int j = k >> 1; j > 0; j >>= 1) {
            for (int i = threadIdx.x; i < N; i += 1024) {
                const int ixj = i ^ j;
                if (ixj > i) {
                    unsigned long long a = keys[i], c = keys[ixj];
                    const bool desc = ((i & k) == 0);
                    if ((a < c) == desc) { keys[i] = c; keys[ixj] = a; }
                }
            }
            __syncthreads();
        }
    }

    for (int i = threadIdx.x; i < K; i += 1024)
        idx_out[b * K + i] = N - 1 - (int)(keys[i] & 0xFFFFFFFFu);
}

// --- Kernel 3: gather selected rows -----------------------------------------
// One wave per output row (b,k): coalesced float4 copy of 1KiB.
__global__ __launch_bounds__(256) void gather_kernel(const float* __restrict__ x,
                                                     const int* __restrict__ idx,
                                                     float* __restrict__ out) {
    const int row  = blockIdx.x * 4 + (threadIdx.x >> 6);    // 0 .. B*K-1
    const int lane = threadIdx.x & 63;
    const int b    = row / K;
    const int src  = idx[row];
    const float4 v = reinterpret_cast<const float4*>(x + ((size_t)b * N + src) * D)[lane];
    reinterpret_cast<float4*>(out + (size_t)row * D)[lane] = v;
}

extern "C" void kernel_launch(void* const* d_in, const int* in_sizes, int n_in,
                              void* d_out, int out_size, void* d_ws, size_t ws_size,
                              hipStream_t stream) {
    const float* x = (const float*)d_in[0];
    float* out = (float*)d_out;

    float* norms = (float*)d_ws;                 // B*N floats = 2 MiB
    int* idx     = (int*)(norms + (size_t)B * N); // B*K ints  = 32 KiB

    norms_kernel<<<B * N / 4, 256, 0, stream>>>(x, norms);
    topk_kernel<<<B, 1024, 0, stream>>>(norms, idx);
    gather_kernel<<<B * K / 4, 256, 0, stream>>>(x, idx, out);
}

// Round 2
// 141.518 us; speedup vs baseline: 1.5892x; 1.5892x over previous
//
#include <hip/hip_runtime.h>

constexpr int B = 64;
constexpr int N = 8192;
constexpr int D = 256;
constexpr int K = 128;

// --- Kernel 1: per-row L2 norm (sum of squares over D) ---------------------
// One wave per row; lane i loads float4 -> wave covers D=256 floats in one
// coalesced 1 KiB access. 6-step shuffle butterfly, lane 0 writes.
__global__ __launch_bounds__(256) void norms_kernel(const float* __restrict__ x,
                                                    float* __restrict__ norms) {
    const int row  = blockIdx.x * 4 + (threadIdx.x >> 6);
    const int lane = threadIdx.x & 63;
    const float4 v = reinterpret_cast<const float4*>(x + (size_t)row * D)[lane];
    float s = v.x * v.x + v.y * v.y + v.z * v.z + v.w * v.w;
    #pragma unroll
    for (int off = 32; off > 0; off >>= 1)
        s += __shfl_xor(s, off, 64);
    if (lane == 0) norms[row] = s;
}

// --- Kernel 2: fused radix-select top-K + gather ----------------------------
// One 1024-thread block per batch. Key = (norm_bits << 32) | (N-1-i):
// norms >= 0 so float bits are monotone as uint; low word makes keys distinct
// and gives lax.top_k's stable tie-break (smaller index ranks higher).
// 8x 8-bit radix-select passes find the exact K-th largest key; collect the
// exactly-K keys >= threshold; rank them with an all-pairs broadcast compare
// (no bitonic sort, no barriers); gather rows wave-per-row.
__global__ __launch_bounds__(1024) void topk_gather_kernel(const float* __restrict__ norms,
                                                           const float* __restrict__ x,
                                                           float* __restrict__ out) {
    __shared__ unsigned long long keys[N];        // 64 KiB
    __shared__ unsigned int hist[256];
    __shared__ unsigned long long s_prefix;
    __shared__ unsigned int s_krem;
    __shared__ unsigned int s_cnt;
    __shared__ unsigned long long cand[K];
    __shared__ int sorted_src[K];

    const int b   = blockIdx.x;
    const int tid = threadIdx.x;
    const float* nb = norms + (size_t)b * N;

    for (int i = tid; i < N; i += 1024) {
        const unsigned int bits = __float_as_uint(nb[i]);   // norms >= 0
        keys[i] = ((unsigned long long)bits << 32) | (unsigned int)(N - 1 - i);
    }
    if (tid == 0) { s_prefix = 0ull; s_krem = K; s_cnt = 0u; }
    __syncthreads();

    // 8-bit-digit radix select for the K-th largest 64-bit key.
    for (int p = 7; p >= 0; --p) {
        const int shift = p * 8;
        // Snapshot state written in the PREVIOUS iteration (barrier-separated).
        const unsigned long long prefix = s_prefix;
        const unsigned int       krem   = s_krem;
        if (tid < 256) hist[tid] = 0u;
        __syncthreads();

        for (int i = tid; i < N; i += 1024) {
            const unsigned long long key = keys[i];
            const bool match = (p == 7) || ((key >> (shift + 8)) == (prefix >> (shift + 8)));
            if (match) atomicAdd(&hist[(unsigned int)(key >> shift) & 255u], 1u);
        }
        __syncthreads();

        if (tid < 256) {
            unsigned int cnt_gt = 0u;                 // keys with larger digit
            for (int d = 255; d > tid; --d) cnt_gt += hist[d];  // broadcast reads
            if (cnt_gt < krem && krem <= cnt_gt + hist[tid]) {  // unique winner
                s_prefix = prefix | ((unsigned long long)tid << shift);
                s_krem   = krem - cnt_gt;
            }
        }
        __syncthreads();
    }

    // Collect exactly K keys >= threshold (keys are distinct).
    const unsigned long long T = s_prefix;
    for (int i = tid; i < N; i += 1024) {
        const unsigned long long key = keys[i];
        if (key >= T) {
            const unsigned int pos = atomicAdd(&s_cnt, 1u);
            cand[pos] = key;
        }
    }
    __syncthreads();

    // Rank by all-pairs compare: rank = #selected keys greater than mine.
    if (tid < K) {
        const unsigned long long key = cand[tid];
        int rank = 0;
        for (int j = 0; j < K; ++j) rank += (cand[j] > key) ? 1 : 0;
        sorted_src[rank] = N - 1 - (int)(key & 0xFFFFFFFFu);
    }
    __syncthreads();

    // Gather: wave per output row, float4 per lane (1 KiB coalesced).
    const int lane = tid & 63;
    for (int r = tid >> 6; r < K; r += 16) {
        const int src = sorted_src[r];
        const float4 v = reinterpret_cast<const float4*>(x + ((size_t)b * N + src) * D)[lane];
        reinterpret_cast<float4*>(out + ((size_t)b * K + r) * D)[lane] = v;
    }
}

extern "C" void kernel_launch(void* const* d_in, const int* in_sizes, int n_in,
                              void* d_out, int out_size, void* d_ws, size_t ws_size,
                              hipStream_t stream) {
    const float* x = (const float*)d_in[0];
    float* out = (float*)d_out;
    float* norms = (float*)d_ws;   // B*N floats = 2 MiB in workspace

    norms_kernel<<<B * N / 4, 256, 0, stream>>>(x, norms);
    topk_gather_kernel<<<B, 1024, 0, stream>>>(norms, x, out);
}

// Round 3
// 125.699 us; speedup vs baseline: 1.7892x; 1.1258x over previous
//
#include <hip/hip_runtime.h>

constexpr int B = 64;
constexpr int N = 8192;
constexpr int D = 256;
constexpr int K = 128;

// --- Kernel 1: per-row L2 norm (sum of squares over D) ---------------------
// One wave per row; lane i loads float4 -> wave covers D=256 floats in one
// coalesced 1 KiB access. 6-step shuffle butterfly, lane 0 writes.
__global__ __launch_bounds__(256) void norms_kernel(const float* __restrict__ x,
                                                    float* __restrict__ norms) {
    const int row  = blockIdx.x * 4 + (threadIdx.x >> 6);
    const int lane = threadIdx.x & 63;
    const float4 v = reinterpret_cast<const float4*>(x + (size_t)row * D)[lane];
    float s = v.x * v.x + v.y * v.y + v.z * v.z + v.w * v.w;
    #pragma unroll
    for (int off = 32; off > 0; off >>= 1)
        s += __shfl_xor(s, off, 64);
    if (lane == 0) norms[row] = s;
}

// --- Kernel 2: fused radix-select top-K + gather ----------------------------
// One 1024-thread block per batch. Key = (norm_bits << 32) | (N-1-i):
// norms >= 0 so float bits are monotone as uint; low word makes keys distinct
// and encodes lax.top_k's stable tie-break (smaller index ranks higher).
//
// Radix-select refinements vs previous round:
//  * MSB pass uses ballot-aggregated histogram updates (concentrated data ->
//    one atomic per wave instead of 8192 serialized same-bin atomics).
//  * Early exit once the selected bucket count == remaining k (threshold
//    fully determined; float norms are distinct well before 8 digits).
//  * Suffix count via 32 segment sums (<=38 iters) instead of <=255.
__global__ __launch_bounds__(1024) void topk_gather_kernel(const float* __restrict__ norms,
                                                           const float* __restrict__ x,
                                                           float* __restrict__ out) {
    __shared__ unsigned long long keys[N];        // 64 KiB
    __shared__ unsigned int hist[256];
    __shared__ unsigned int seg[32];
    __shared__ unsigned long long s_prefix;
    __shared__ unsigned int s_krem;
    __shared__ int s_done;
    __shared__ unsigned int s_cnt;
    __shared__ unsigned long long cand[K];
    __shared__ int sorted_src[K];

    const int b    = blockIdx.x;
    const int tid  = threadIdx.x;
    const int lane = tid & 63;
    const float* nb = norms + (size_t)b * N;

    for (int i = tid; i < N; i += 1024) {
        const unsigned int bits = __float_as_uint(nb[i]);   // norms >= 0
        keys[i] = ((unsigned long long)bits << 32) | (unsigned int)(N - 1 - i);
    }
    if (tid == 0) { s_prefix = 0ull; s_krem = K; s_done = 0; s_cnt = 0u; }
    __syncthreads();

    for (int p = 7; p >= 0; --p) {
        if (s_done) break;                         // written pre-barrier, uniform
        const int shift = p * 8;
        const unsigned long long prefix = s_prefix; // prev-pass state (barrier-separated)
        const unsigned int       krem   = s_krem;
        if (tid < 256) hist[tid] = 0u;
        __syncthreads();

        if (p == 7) {
            // All keys participate; digits are heavily duplicated (float
            // exponent concentration) -> ballot-aggregate per wave.
            for (int i = tid; i < N; i += 1024) {
                const unsigned int d = (unsigned int)(keys[i] >> 56);
                unsigned long long rem = __ballot(true);
                while (rem) {
                    const int leader = __ffsll(rem) - 1;
                    const unsigned int dl = __shfl(d, leader, 64);
                    const unsigned long long grp = __ballot(d == dl);
                    if (lane == leader) atomicAdd(&hist[dl], (unsigned int)__popcll(grp));
                    rem &= ~grp;
                }
            }
        } else {
            for (int i = tid; i < N; i += 1024) {
                const unsigned long long key = keys[i];
                if ((key >> (shift + 8)) == (prefix >> (shift + 8)))
                    atomicAdd(&hist[(unsigned int)(key >> shift) & 255u], 1u);
            }
        }
        __syncthreads();

        if (tid < 32) {                            // segment sums of 8 bins
            unsigned int s = 0;
            #pragma unroll
            for (int d2 = 0; d2 < 8; ++d2) s += hist[tid * 8 + d2];
            seg[tid] = s;
        }
        __syncthreads();

        if (tid < 256) {
            unsigned int cnt_gt = 0;
            const int hiSeg = (tid >> 3) + 1;
            for (int s2 = hiSeg; s2 < 32; ++s2) cnt_gt += seg[s2];
            for (int d2 = tid + 1; d2 < hiSeg * 8; ++d2) cnt_gt += hist[d2];
            const unsigned int h = hist[tid];
            if (cnt_gt < krem && krem <= cnt_gt + h) {   // unique winner thread
                s_prefix = prefix | ((unsigned long long)tid << shift);
                s_krem   = krem - cnt_gt;
                if (h == krem - cnt_gt) s_done = 1;      // bucket fully selected
            }
        }
        __syncthreads();
    }

    // Collect exactly K keys >= threshold (keys distinct; on early exit the
    // threshold's low bits are zero and the count is exactly K by invariant).
    const unsigned long long T = s_prefix;
    for (int i = tid; i < N; i += 1024) {
        const unsigned long long key = keys[i];
        if (key >= T) {
            const unsigned int pos = atomicAdd(&s_cnt, 1u);
            cand[pos] = key;
        }
    }
    __syncthreads();

    // Rank by all-pairs compare: rank = #selected keys greater than mine.
    if (tid < K) {
        const unsigned long long key = cand[tid];
        int rank = 0;
        for (int j = 0; j < K; ++j) rank += (cand[j] > key) ? 1 : 0;
        sorted_src[rank] = N - 1 - (int)(key & 0xFFFFFFFFu);
    }
    __syncthreads();

    // Gather: wave per output row, float4 per lane (1 KiB coalesced).
    for (int r = tid >> 6; r < K; r += 16) {
        const int src = sorted_src[r];
        const float4 v = reinterpret_cast<const float4*>(x + ((size_t)b * N + src) * D)[lane];
        reinterpret_cast<float4*>(out + ((size_t)b * K + r) * D)[lane] = v;
    }
}

extern "C" void kernel_launch(void* const* d_in, const int* in_sizes, int n_in,
                              void* d_out, int out_size, void* d_ws, size_t ws_size,
                              hipStream_t stream) {
    const float* x = (const float*)d_in[0];
    float* out = (float*)d_out;
    float* norms = (float*)d_ws;   // B*N floats = 2 MiB in workspace

    norms_kernel<<<B * N / 4, 256, 0, stream>>>(x, norms);
    topk_gather_kernel<<<B, 1024, 0, stream>>>(norms, x, out);
}

// Round 4
// 123.915 us; speedup vs baseline: 1.8150x; 1.0144x over previous
//
#include <hip/hip_runtime.h>

constexpr int B = 64;
constexpr int N = 8192;
constexpr int D = 256;
constexpr int K = 128;
constexpr int CHUNKS = 32;                 // chunks per batch
constexpr int RPC = N / CHUNKS;            // 256 rows per chunk
constexpr int NCAND = CHUNKS * K;          // 4096 candidates per batch

// --- Stage 1: fused norm + local top-K select -------------------------------
// 2048 blocks (batch x chunk) of 256 threads. Wave-per-row float4 loads
// (identical summation order to previous rounds). The 256 row-keys of the
// chunk land in LDS; each thread ranks its key via 256 broadcast compares and
// the top 128 write themselves to ws at their rank (no atomics, sorted).
// Any global top-128 key is a local top-128 key, so candidates are sufficient.
__global__ __launch_bounds__(256) void norm_select_kernel(const float* __restrict__ x,
                                                          unsigned long long* __restrict__ cand) {
    __shared__ unsigned long long skeys[RPC];
    const int bid   = blockIdx.x;
    const int batch = bid >> 5;            // /CHUNKS
    const int chunk = bid & (CHUNKS - 1);
    const int w     = threadIdx.x >> 6;
    const int lane  = threadIdx.x & 63;
    const size_t rowbase = (size_t)batch * N + (size_t)chunk * RPC;

    // Each of 4 waves reduces 64 consecutive rows.
    const int lrow0 = w * 64;
    for (int it = 0; it < 64; ++it) {
        const int lrow = lrow0 + it;
        const float4 v = reinterpret_cast<const float4*>(x + (rowbase + lrow) * D)[lane];
        float s = v.x * v.x + v.y * v.y + v.z * v.z + v.w * v.w;
        #pragma unroll
        for (int off = 32; off > 0; off >>= 1)
            s += __shfl_xor(s, off, 64);
        if (lane == 0) {
            const int grow = chunk * RPC + lrow;              // row index in batch
            skeys[lrow] = ((unsigned long long)__float_as_uint(s) << 32)
                        | (unsigned int)(N - 1 - grow);       // stable tie-break
        }
    }
    __syncthreads();

    // All-pairs rank among the chunk's 256 distinct keys (broadcast reads).
    const unsigned long long mine = skeys[threadIdx.x];
    int rank = 0;
    for (int j = 0; j < RPC; ++j)
        rank += (skeys[j] > mine) ? 1 : 0;
    if (rank < K)
        cand[(size_t)bid * K + rank] = mine;                  // unique slot
}

// --- Stage 2: exact top-K over 4096 candidates + fused gather ---------------
// One 1024-thread block per batch. Radix-select (8-bit digits, MSB-first,
// ballot-aggregated MSB histogram, early exit) finds the exact K-th largest
// key; collect the exactly-K keys >= threshold; all-pairs rank; gather.
__global__ __launch_bounds__(1024) void topk_gather_kernel(const unsigned long long* __restrict__ cand_in,
                                                           const float* __restrict__ x,
                                                           float* __restrict__ out) {
    __shared__ unsigned long long keys[NCAND];    // 32 KiB
    __shared__ unsigned int hist[256];
    __shared__ unsigned int seg[32];
    __shared__ unsigned long long s_prefix;
    __shared__ unsigned int s_krem;
    __shared__ int s_done;
    __shared__ unsigned int s_cnt;
    __shared__ unsigned long long sel[K];
    __shared__ int sorted_src[K];

    const int b    = blockIdx.x;
    const int tid  = threadIdx.x;
    const int lane = tid & 63;

    for (int i = tid; i < NCAND; i += 1024)
        keys[i] = cand_in[(size_t)b * NCAND + i];
    if (tid == 0) { s_prefix = 0ull; s_krem = K; s_done = 0; s_cnt = 0u; }
    __syncthreads();

    for (int p = 7; p >= 0; --p) {
        if (s_done) break;                         // uniform, barrier-separated
        const int shift = p * 8;
        const unsigned long long prefix = s_prefix;
        const unsigned int       krem   = s_krem;
        if (tid < 256) hist[tid] = 0u;
        __syncthreads();

        if (p == 7) {
            // Digits heavily duplicated (float exponent concentration):
            // ballot-aggregate one atomic per distinct digit per wave.
            for (int i = tid; i < NCAND; i += 1024) {
                const unsigned int d = (unsigned int)(keys[i] >> 56);
                unsigned long long rem = __ballot(true);
                while (rem) {
                    const int leader = __ffsll(rem) - 1;
                    const unsigned int dl = __shfl(d, leader, 64);
                    const unsigned long long grp = __ballot(d == dl);
                    if (lane == leader) atomicAdd(&hist[dl], (unsigned int)__popcll(grp));
                    rem &= ~grp;
                }
            }
        } else {
            for (int i = tid; i < NCAND; i += 1024) {
                const unsigned long long key = keys[i];
                if ((key >> (shift + 8)) == (prefix >> (shift + 8)))
                    atomicAdd(&hist[(unsigned int)(key >> shift) & 255u], 1u);
            }
        }
        __syncthreads();

        if (tid < 32) {                            // segment sums of 8 bins
            unsigned int s = 0;
            #pragma unroll
            for (int d2 = 0; d2 < 8; ++d2) s += hist[tid * 8 + d2];
            seg[tid] = s;
        }
        __syncthreads();

        if (tid < 256) {
            unsigned int cnt_gt = 0;
            const int hiSeg = (tid >> 3) + 1;
            for (int s2 = hiSeg; s2 < 32; ++s2) cnt_gt += seg[s2];
            for (int d2 = tid + 1; d2 < hiSeg * 8; ++d2) cnt_gt += hist[d2];
            const unsigned int h = hist[tid];
            if (cnt_gt < krem && krem <= cnt_gt + h) {   // unique winner
                s_prefix = prefix | ((unsigned long long)tid << shift);
                s_krem   = krem - cnt_gt;
                if (h == krem - cnt_gt) s_done = 1;
            }
        }
        __syncthreads();
    }

    // Collect exactly K keys >= threshold (keys distinct).
    const unsigned long long T = s_prefix;
    for (int i = tid; i < NCAND; i += 1024) {
        const unsigned long long key = keys[i];
        if (key >= T) {
            const unsigned int pos = atomicAdd(&s_cnt, 1u);
            sel[pos] = key;
        }
    }
    __syncthreads();

    // Rank by all-pairs compare: rank = #selected keys greater than mine.
    if (tid < K) {
        const unsigned long long key = sel[tid];
        int rank = 0;
        for (int j = 0; j < K; ++j) rank += (sel[j] > key) ? 1 : 0;
        sorted_src[rank] = N - 1 - (int)(key & 0xFFFFFFFFu);
    }
    __syncthreads();

    // Gather: wave per output row, float4 per lane (1 KiB coalesced).
    for (int r = tid >> 6; r < K; r += 16) {
        const int src = sorted_src[r];
        const float4 v = reinterpret_cast<const float4*>(x + ((size_t)b * N + src) * D)[lane];
        reinterpret_cast<float4*>(out + ((size_t)b * K + r) * D)[lane] = v;
    }
}

extern "C" void kernel_launch(void* const* d_in, const int* in_sizes, int n_in,
                              void* d_out, int out_size, void* d_ws, size_t ws_size,
                              hipStream_t stream) {
    const float* x = (const float*)d_in[0];
    float* out = (float*)d_out;
    unsigned long long* cand = (unsigned long long*)d_ws;   // B*NCAND u64 = 2 MiB

    norm_select_kernel<<<B * CHUNKS, 256, 0, stream>>>(x, cand);
    topk_gather_kernel<<<B, 1024, 0, stream>>>(cand, x, out);
}